// Round 5
// baseline (230.304 us; speedup 1.0000x reference)
//
#include <hip/hip_runtime.h>
#include <hip/hip_fp8.h>
#include <math.h>

#define N_NODES 50000
#define N_EDGES 800000
#define NP 4                      // node partitions (12500 nodes each)
#define NS 64                     // edge segments (12500 edges each)
#define PSZ (N_NODES / NP)        // 12500
#define SSZ (N_EDGES / NS)        // 12500
#define NB 196                    // ceil(N/256)

typedef _Float16 half8 __attribute__((ext_vector_type(8)));
typedef float floatx4 __attribute__((ext_vector_type(4)));

// ---------------- fp8 e4m3 (OCP) helpers — HW cvt on gfx950 ----------------
__device__ __forceinline__ unsigned char f_to_fp8(float f) {
    __hip_fp8_e4m3 q(f);
    return (unsigned char)q.__x;
}
__device__ __forceinline__ float fp8_to_f(unsigned char u) {
    __hip_fp8_e4m3 q;
    q.__x = (__hip_fp8_storage_t)u;
    return (float)q;
}

// ---------------------------------------------------------------------------
// Fused: partitioned LDS histogram (blocks 0..NP*NS-1) + WT transpose +
// gacc/gcnt zeroing. Packed u32 counters (in low16 / out high16); the
// atomicAdd return's low bits are the edge's within-segment rank (u8).
// NP=4: 50 KB LDS => 3 blocks/CU; edges re-read 4x.
// ---------------------------------------------------------------------------
__global__ __launch_bounds__(256) void hist_wt_kernel(const int* __restrict__ src,
                                                      const int* __restrict__ dst,
                                                      unsigned char* __restrict__ inpart,
                                                      unsigned char* __restrict__ outpart,
                                                      unsigned char* __restrict__ rank,
                                                      const float* __restrict__ W2,
                                                      const float* __restrict__ W3,
                                                      const float* __restrict__ W4,
                                                      _Float16* __restrict__ WT,
                                                      float* __restrict__ gacc) {
    __shared__ int h[PSZ + 4];                   // 12504 ints = 50016 B
    if (blockIdx.x >= NP * NS) {
        int wb = blockIdx.x - NP * NS;
        if (wb < 48) {                           // WT transpose: f32 [k][n] -> f16 [n][k]
            int i = wb * 256 + threadIdx.x;
            if (i < 3 * 4096) {
                int l = i >> 12;
                int r = i & 4095;
                int k = r >> 6, n = r & 63;
                const float* W = (l == 0) ? W2 : (l == 1) ? W3 : W4;
                WT[l * 4096 + n * 64 + k] = (_Float16)W[r];
            }
        } else {                                 // zero gacc[4096] + gcnt[64]
            for (int i = threadIdx.x; i < 64 * 64 + 64; i += 256) gacc[i] = 0.0f;
        }
        return;
    }
    int p = blockIdx.x / NS, s = blockIdx.x % NS;
    for (int i = threadIdx.x; i < (PSZ + 4) / 4; i += 256)
        ((int4*)h)[i] = make_int4(0, 0, 0, 0);
    __syncthreads();
    int lo = p * PSZ;
    int ebase = s * SSZ;
    const int4* d4 = (const int4*)(dst + ebase);
    const int4* s4 = (const int4*)(src + ebase);
    unsigned char* rk = rank + ebase;
    for (int i = threadIdx.x; i < SSZ / 4; i += 256) {
        int4 d = d4[i];
        int4 sv = s4[i];
        int t;
        t = d.x - lo;  if ((unsigned)t < PSZ) rk[4 * i + 0] = (unsigned char)(atomicAdd(&h[t], 1) & 0xffff);
        t = d.y - lo;  if ((unsigned)t < PSZ) rk[4 * i + 1] = (unsigned char)(atomicAdd(&h[t], 1) & 0xffff);
        t = d.z - lo;  if ((unsigned)t < PSZ) rk[4 * i + 2] = (unsigned char)(atomicAdd(&h[t], 1) & 0xffff);
        t = d.w - lo;  if ((unsigned)t < PSZ) rk[4 * i + 3] = (unsigned char)(atomicAdd(&h[t], 1) & 0xffff);
        t = sv.x - lo; if ((unsigned)t < PSZ) atomicAdd(&h[t], 0x10000);
        t = sv.y - lo; if ((unsigned)t < PSZ) atomicAdd(&h[t], 0x10000);
        t = sv.z - lo; if ((unsigned)t < PSZ) atomicAdd(&h[t], 0x10000);
        t = sv.w - lo; if ((unsigned)t < PSZ) atomicAdd(&h[t], 0x10000);
    }
    __syncthreads();
    unsigned char* ip = inpart + (size_t)s * N_NODES + lo;
    unsigned char* op = outpart + (size_t)s * N_NODES + lo;
    for (int i = threadIdx.x; i < PSZ / 2; i += 256) {
        int v0 = h[2 * i], v1 = h[2 * i + 1];
        uchar2 iv, ov;
        iv.x = (unsigned char)(v0 & 0xff);
        iv.y = (unsigned char)(v1 & 0xff);
        ov.x = (unsigned char)((v0 >> 16) & 0xff);
        ov.y = (unsigned char)((v1 >> 16) & 0xff);
        ((uchar2*)ip)[i] = iv;
        ((uchar2*)op)[i] = ov;
    }
}

// ---------------------------------------------------------------------------
// Fused: reduce u8 segment partials -> degrees AND rewrite inpart in place
// into the exclusive within-row segment prefix; features/norms (fp8 table);
// block scan; per-graph node counts.
// ---------------------------------------------------------------------------
__global__ void scan_block_feat_kernel(unsigned char* __restrict__ inpart,
                                       const unsigned char* __restrict__ outpart,
                                       const int* __restrict__ graph_ids,
                                       int* __restrict__ row_start, int* __restrict__ blk_sums,
                                       float* __restrict__ norm_src, float* __restrict__ norm_dst,
                                       uchar4* __restrict__ hs0, float* __restrict__ gcnt, int N) {
    __shared__ int ghist[64];
    if (threadIdx.x < 64) ghist[threadIdx.x] = 0;
    int i = blockIdx.x * 256 + threadIdx.x;
    int din_i = 0, dout_i = 0;
    if (i < N) {
        unsigned char run = 0;
#pragma unroll
        for (int s = 0; s < NS; ++s) {
            unsigned char c = inpart[(size_t)s * N_NODES + i];
            inpart[(size_t)s * N_NODES + i] = run;     // prefix rewrite in place
            run = (unsigned char)(run + c);
            dout_i += outpart[(size_t)s * N_NODES + i];
        }
        din_i = (int)run;
        float din = (float)din_i;
        float dout = (float)dout_i;
        float ns = 1.0f / sqrtf(fmaxf(dout, 1.0f));
        float nd = 1.0f / sqrtf(fmaxf(din, 1.0f));
        norm_src[i] = ns;
        norm_dst[i] = nd;
        float h1 = din;
        float h2 = (din - 3.0f > 0.0f) ? 1.0f : 0.0f;
        float h3 = 3.0f / din;
        float h4 = (din - 4.0f > 0.0f) ? 1.0f : 0.0f;
        uchar4 q;
        q.x = f_to_fp8(h1 * ns);
        q.y = f_to_fp8(h2 * ns);
        q.z = f_to_fp8(h3 * ns);
        q.w = f_to_fp8(h4 * ns);
        hs0[i] = q;
    }
    __syncthreads();
    if (i < N) atomicAdd(&ghist[graph_ids[i]], 1);
    int lane = threadIdx.x & 63;
    int wid = threadIdx.x >> 6;
    int x = din_i;
#pragma unroll
    for (int off = 1; off < 64; off <<= 1) {
        int t = __shfl_up(x, off);
        if (lane >= off) x += t;
    }
    __shared__ int wsum[4];
    if (lane == 63) wsum[wid] = x;
    __syncthreads();
    int woff = 0;
    for (int w = 0; w < wid; ++w) woff += wsum[w];
    int incl = x + woff;
    if (i < N) row_start[i] = incl - din_i;
    if (threadIdx.x == 255) blk_sums[blockIdx.x] = incl;
    if (threadIdx.x < 64 && ghist[threadIdx.x] > 0)
        atomicAdd(&gcnt[threadIdx.x], (float)ghist[threadIdx.x]);
}

// ---------------------------------------------------------------------------
// Slim: finalize row_start only (each block re-scans the 196 block sums).
// ---------------------------------------------------------------------------
__global__ void row_add_kernel(int* __restrict__ row_start,
                               const int* __restrict__ blk_sums, int N) {
    __shared__ int sOff[256];
    int t = threadIdx.x;
    int v = (t < NB) ? blk_sums[t] : 0;
    int lane = t & 63;
    int wid = t >> 6;
    int x = v;
#pragma unroll
    for (int off = 1; off < 64; off <<= 1) {
        int tt = __shfl_up(x, off);
        if (lane >= off) x += tt;
    }
    __shared__ int wsum[4];
    if (lane == 63) wsum[wid] = x;
    __syncthreads();
    int woff = 0;
    for (int w = 0; w < wid; ++w) woff += wsum[w];
    sOff[t] = x + woff - v;              // exclusive prefix of blk_sums
    __syncthreads();
    int i = blockIdx.x * 256 + threadIdx.x;
    if (blockIdx.x == 0 && threadIdx.x == 0) row_start[N] = N_EDGES;
    if (i < N) row_start[i] += sOff[blockIdx.x];
}

// ---------------------------------------------------------------------------
// Rank-based CSR fill: pos = row_start[d] + pref[s][d] + rank[e].
// csr_src is u16 (node ids < 50000 < 65536).
// ---------------------------------------------------------------------------
__global__ __launch_bounds__(256) void csr_fill_kernel(const int* __restrict__ src,
                                                       const int* __restrict__ dst,
                                                       const int* __restrict__ row_start,
                                                       const unsigned char* __restrict__ inpart,
                                                       const unsigned char* __restrict__ rank,
                                                       unsigned short* __restrict__ csr_src) {
    int i = blockIdx.x * 256 + threadIdx.x;          // edge-quad index
    if (i >= N_EDGES / 4) return;
    int4 d = ((const int4*)dst)[i];
    int4 sv = ((const int4*)src)[i];
    uchar4 rk = ((const uchar4*)rank)[i];
    int s = (4 * i) / SSZ;                           // uniform per SSZ/4 quads
    const unsigned char* pref = inpart + (size_t)s * N_NODES;
    csr_src[row_start[d.x] + (int)pref[d.x] + (int)rk.x] = (unsigned short)sv.x;
    csr_src[row_start[d.y] + (int)pref[d.y] + (int)rk.y] = (unsigned short)sv.y;
    csr_src[row_start[d.z] + (int)pref[d.z] + (int)rk.z] = (unsigned short)sv.z;
    csr_src[row_start[d.w] + (int)pref[d.w] + (int)rk.w] = (unsigned short)sv.w;
}

// ---------------------------------------------------------------------------
// Layer 1: IN=4 -> H=64. fp8x4 gather table (200 KB, L2-hot).
// ---------------------------------------------------------------------------
__global__ void conv4_kernel(const uchar4* __restrict__ hs0,
                             const int* __restrict__ row_start,
                             const unsigned short* __restrict__ csr_src,
                             const float* __restrict__ norm_src,
                             const float* __restrict__ norm_dst,
                             const float* __restrict__ W, const float* __restrict__ b,
                             unsigned char* __restrict__ out, int N) {
    __shared__ float sW[4 * 64];
    __shared__ float sb[64];
    sW[threadIdx.x] = W[threadIdx.x];
    if (threadIdx.x < 64) sb[threadIdx.x] = b[threadIdx.x];
    __syncthreads();
    int lane = threadIdx.x & 63;
    int wid = threadIdx.x >> 6;
    int v = blockIdx.x * 4 + wid;
    if (v >= N) return;
    int rs = row_start[v], re = row_start[v + 1];
    float ax = 0.f, ay = 0.f, az = 0.f, aw = 0.f;
    for (int e = rs + lane; e < re; e += 64) {
        uchar4 f = hs0[csr_src[e]];
        ax += fp8_to_f(f.x); ay += fp8_to_f(f.y);
        az += fp8_to_f(f.z); aw += fp8_to_f(f.w);
    }
#pragma unroll
    for (int off = 32; off; off >>= 1) {
        ax += __shfl_xor(ax, off);
        ay += __shfl_xor(ay, off);
        az += __shfl_xor(az, off);
        aw += __shfl_xor(aw, off);
    }
    float nd = norm_dst[v];
    float r = sb[lane] + nd * (ax * sW[lane] + ay * sW[64 + lane] +
                               az * sW[128 + lane] + aw * sW[192 + lane]);
    r = fmaxf(r, 0.0f) * norm_src[v];
    out[(size_t)v * 64 + lane] = f_to_fp8(r);
}

// ---------------------------------------------------------------------------
// Layers 2-4: H=64 -> H=64. ONE WAVE PER BLOCK (64 threads), 8 nodes/wave.
// R5 theory: conv64 is gather-LATENCY bound (R1 VMEM-count null, R4
// footprint null, R3 fence-poison scaling fits L2-hit latency). So:
//  * 1-wave blocks: finer CU scheduling granularity, smoother drain tail.
//  * TRIPLE-buffered pipeline (t0/t1/t2): 32 gather loads in flight during
//    each 16-edge ACCUM (was 16). Numerics bit-identical (same order).
// ---------------------------------------------------------------------------
#define LOADIDX(MY, E0)  MY = (int)csr_src[(E0) + (lane & 15)];

#define GATHER(T, MY)                                                   \
    _Pragma("unroll")                                                   \
    for (int j = 0; j < 16; ++j) {                                      \
        unsigned uu = (unsigned)__builtin_amdgcn_readlane(MY, j);       \
        if (uu >= (unsigned)N_NODES) uu = 0;                            \
        T[j] = hs_in[(uu << 6) + (unsigned)lane];                       \
    }

#define ACCUM(T)                                                        \
    _Pragma("unroll")                                                   \
    for (int j = 0; j < 16; ++j) {                                      \
        while (ecur == bound) {                                         \
            float ndc = __uint_as_float(                                \
                (unsigned)__builtin_amdgcn_readlane((int)nd8u, cur - vbase)); \
            sAgg[cur - vbase][lane] = (_Float16)(acc * ndc);            \
            acc = 0.0f;                                                 \
            ++cur;                                                      \
            bound = (cur < vend)                                        \
                        ? __builtin_amdgcn_readlane(rb8, cur - vbase)   \
                        : 0x7fffffff;                                   \
        }                                                               \
        acc += fp8_to_f(T[j]);                                         \
        ++ecur;                                                         \
    }

__global__ __launch_bounds__(64) void conv64_kernel(
        const unsigned char* __restrict__ hs_in,
        const int* __restrict__ row_start,
        const unsigned short* __restrict__ csr_src,
        const float* __restrict__ norm_src,
        const float* __restrict__ norm_dst,
        const _Float16* __restrict__ WT, const float* __restrict__ b,
        unsigned char* __restrict__ out8,
        const int* __restrict__ graph_ids, float* __restrict__ gacc,
        int do_pool, int N) {
    __shared__ _Float16 sAgg[16][72];
    const int lane = threadIdx.x & 63;
    const int vbase = blockIdx.x * 8;
    if (vbase >= N) return;

    const int vend = vbase + 8;                   // N % 8 == 0 => always full
    const int rb8 = row_start[vbase + 1 + (lane & 7)];
    const unsigned nd8u = __float_as_uint(norm_dst[vbase + (lane & 7)]);
    const unsigned ns8u = __float_as_uint(norm_src[vbase + (lane & 7)]);
    const int rs = row_start[vbase];
    const int re = __builtin_amdgcn_readlane(rb8, 7);
    int cur = vbase;
    int bound = __builtin_amdgcn_readlane(rb8, 0);
    int ecur = rs;
    float acc = 0.0f;
    int nbp = (re - rs + 15) >> 4;
    int e = rs;
    int my0, my1, my2;
    unsigned char t0[16], t1[16], t2[16];

    if (nbp > 0) {
        LOADIDX(my0, e);
        GATHER(t0, my0);
        LOADIDX(my1, e + 16);
        GATHER(t1, my1);
        LOADIDX(my2, e + 32);
        int k = 0;
        while (k + 3 <= nbp) {
            GATHER(t2, my2);  LOADIDX(my0, e + 48);  ACCUM(t0);
            GATHER(t0, my0);  LOADIDX(my1, e + 64);  ACCUM(t1);
            GATHER(t1, my1);  LOADIDX(my2, e + 80);  ACCUM(t2);
            k += 3; e += 48;
        }
        int r = nbp - k;
        if (r >= 1) { ACCUM(t0); }
        if (r >= 2) { ACCUM(t1); }
    }
    while (cur < vend) {
        float ndc = __uint_as_float(
            (unsigned)__builtin_amdgcn_readlane((int)nd8u, cur - vbase));
        sAgg[cur - vbase][lane] = (_Float16)(acc * ndc);
        acc = 0.0f;
        ++cur;
    }

    const int l15 = lane & 15;
    const int quad = lane >> 4;
    const _Float16* aRow = &sAgg[l15][quad * 8];
    half8 a0 = *(const half8*)(aRow);
    half8 a1 = *(const half8*)(aRow + 32);

    floatx4 c[4];
#pragma unroll
    for (int nt = 0; nt < 4; ++nt) c[nt] = (floatx4){0.f, 0.f, 0.f, 0.f};

#pragma unroll
    for (int nt = 0; nt < 4; ++nt) {
        const _Float16* bp = WT + ((size_t)(nt * 16 + l15)) * 64 + quad * 8;
        half8 b0 = *(const half8*)bp;
        half8 b1 = *(const half8*)(bp + 32);
        c[nt] = __builtin_amdgcn_mfma_f32_16x16x32_f16(a0, b0, c[nt], 0, 0, 0);
        c[nt] = __builtin_amdgcn_mfma_f32_16x16x32_f16(a1, b1, c[nt], 0, 0, 0);
    }

    if (do_pool) {
        int g0 = graph_ids[vbase];                 // wave-uniform s_loads
        int g7 = graph_ids[vbase + 7];
        if (g0 == g7) {
#pragma unroll
            for (int nt = 0; nt < 4; ++nt) {
                float bias = b[nt * 16 + l15];
                float fsum = 0.0f;
                if (quad < 2) {
#pragma unroll
                    for (int r = 0; r < 4; ++r)
                        fsum += fmaxf(c[nt][r] + bias, 0.0f);
                }
                fsum += __shfl_xor(fsum, 16);      // quad0 + quad1
                if (quad == 0)
                    atomicAdd(&gacc[g0 * 64 + nt * 16 + l15], fsum);
            }
        } else {
#pragma unroll
            for (int nt = 0; nt < 4; ++nt) {
                float bias = b[nt * 16 + l15];
#pragma unroll
                for (int r = 0; r < 4; ++r) {
                    int m = quad * 4 + r;
                    if (m < 8) {
                        int v = vbase + m;
                        float val = fmaxf(c[nt][r] + bias, 0.0f);
                        atomicAdd(&gacc[graph_ids[v] * 64 + nt * 16 + l15], val);
                    }
                }
            }
        }
    } else {
#pragma unroll
        for (int nt = 0; nt < 4; ++nt) {
            float bias = b[nt * 16 + l15];
#pragma unroll
            for (int r = 0; r < 4; ++r) {
                int m = quad * 4 + r;
                int v = vbase + m;
                if (m < 8 && v < N) {
                    float nsv = __uint_as_float(
                        (unsigned)__builtin_amdgcn_readlane((int)ns8u, m));
                    float val = fmaxf(c[nt][r] + bias, 0.0f) * nsv;
                    out8[(size_t)v * 64 + nt * 16 + l15] = f_to_fp8(val);
                }
            }
        }
    }
}

// ---------------------------------------------------------------------------
// Pool stage 2: one wave per graph (16 blocks x 4 waves).
// ---------------------------------------------------------------------------
__global__ void pool2_kernel(const float* __restrict__ gacc, const float* __restrict__ gcnt,
                             const float* __restrict__ Wout, const float* __restrict__ bout,
                             float* __restrict__ out) {
    int lane = threadIdx.x & 63;
    int g = blockIdx.x * 4 + (threadIdx.x >> 6);   // 64 waves total
    float p = (gacc[g * 64 + lane] / gcnt[g]) * Wout[lane];
#pragma unroll
    for (int off = 32; off; off >>= 1) p += __shfl_xor(p, off);
    if (lane == 0) out[g] = 1.0f / (1.0f + expf(-(p + bout[0])));
}

// ---------------------------------------------------------------------------
extern "C" void kernel_launch(void* const* d_in, const int* in_sizes, int n_in,
                              void* d_out, int out_size, void* d_ws, size_t ws_size,
                              hipStream_t stream) {
    const int* src = (const int*)d_in[0];
    const int* dst = (const int*)d_in[1];
    const int* graph_ids = (const int*)d_in[2];
    const float* W1 = (const float*)d_in[3];
    const float* b1 = (const float*)d_in[4];
    const float* W2 = (const float*)d_in[5];
    const float* b2 = (const float*)d_in[6];
    const float* W3 = (const float*)d_in[7];
    const float* b3 = (const float*)d_in[8];
    const float* W4 = (const float*)d_in[9];
    const float* b4 = (const float*)d_in[10];
    const float* Wout = (const float*)d_in[11];
    const float* bout = (const float*)d_in[12];
    float* out = (float*)d_out;

    const int N = N_NODES, E = N_EDGES;

    unsigned char* buf8A = (unsigned char*)d_ws;           // N*64 fp8
    unsigned char* buf8B = buf8A + (size_t)N * 64;         // N*64 fp8
    _Float16* WT   = (_Float16*)(buf8B + (size_t)N * 64);  // 3*4096 f16
    float* gacc = (float*)(WT + 3 * 4096);                 // 64*64 f32
    float* gcnt = gacc + 64 * 64;                          // 64 f32
    unsigned char* hs0 = (unsigned char*)(gcnt + 64);      // N*4 fp8 (4B-aligned)
    float* norm_src = (float*)(hs0 + (size_t)N * 4);       // N
    float* norm_dst = norm_src + N;                        // N
    unsigned short* csr_src = (unsigned short*)(norm_dst + N);   // E u16
    int* row_start = (int*)(csr_src + E);                  // N+1
    int* blk_sums  = row_start + (N + 1);                  // NB
    unsigned char* inpart  = (unsigned char*)(blk_sums + NB + 1);    // NS*N u8
    unsigned char* outpart = inpart + (size_t)NS * N;                // NS*N u8
    unsigned char* rank    = outpart + (size_t)NS * N;               // E u8

    // hist (256) + WT transpose (48) + gacc/gcnt zero (1)
    hist_wt_kernel<<<NP * NS + 49, 256, 0, stream>>>(src, dst, inpart, outpart, rank,
                                                     W2, W3, W4, WT, gacc);
    scan_block_feat_kernel<<<NB, 256, 0, stream>>>(inpart, outpart, graph_ids,
                                                   row_start, blk_sums,
                                                   norm_src, norm_dst, (uchar4*)hs0, gcnt, N);
    row_add_kernel<<<NB, 256, 0, stream>>>(row_start, blk_sums, N);
    csr_fill_kernel<<<(E / 4 + 255) / 256, 256, 0, stream>>>(src, dst, row_start, inpart,
                                                             rank, csr_src);

    conv4_kernel<<<(N + 3) / 4, 256, 0, stream>>>((const uchar4*)hs0, row_start, csr_src,
                                                  norm_src, norm_dst, W1, b1, buf8A, N);
    const int CB = N / 8;           // one 64-thread wave per block, 8 nodes
    conv64_kernel<<<CB, 64, 0, stream>>>(buf8A, row_start, csr_src, norm_src, norm_dst,
                                         WT + 0 * 4096, b2, buf8B, graph_ids, gacc, 0, N);
    conv64_kernel<<<CB, 64, 0, stream>>>(buf8B, row_start, csr_src, norm_src, norm_dst,
                                         WT + 1 * 4096, b3, buf8A, graph_ids, gacc, 0, N);
    conv64_kernel<<<CB, 64, 0, stream>>>(buf8A, row_start, csr_src, norm_src, norm_dst,
                                         WT + 2 * 4096, b4, (unsigned char*)nullptr,
                                         graph_ids, gacc, 1, N);

    pool2_kernel<<<16, 256, 0, stream>>>(gacc, gcnt, Wout, bout, out);
}

// Round 6
// 194.046 us; speedup vs baseline: 1.1869x; 1.1869x over previous
//
#include <hip/hip_runtime.h>
#include <hip/hip_fp8.h>
#include <math.h>

#define N_NODES 50000
#define N_EDGES 800000
#define NP 4                      // node partitions (12500 nodes each)
#define NS 64                     // edge segments (12500 edges each)
#define PSZ (N_NODES / NP)        // 12500
#define SSZ (N_EDGES / NS)        // 12500
#define NB 196                    // ceil(N/256)

typedef _Float16 half8 __attribute__((ext_vector_type(8)));
typedef float floatx4 __attribute__((ext_vector_type(4)));

// ---------------- fp8 e4m3 (OCP) helpers — HW cvt on gfx950 ----------------
__device__ __forceinline__ unsigned char f_to_fp8(float f) {
    __hip_fp8_e4m3 q(f);
    return (unsigned char)q.__x;
}
__device__ __forceinline__ float fp8_to_f(unsigned char u) {
    __hip_fp8_e4m3 q;
    q.__x = (__hip_fp8_storage_t)u;
    return (float)q;
}

// ---------------------------------------------------------------------------
// Fused: partitioned LDS histogram (blocks 0..NP*NS-1) + WT transpose +
// gacc/gcnt zeroing. Packed u32 counters (in low16 / out high16); the
// atomicAdd return's low bits are the edge's within-segment rank (u8).
// ---------------------------------------------------------------------------
__global__ __launch_bounds__(256) void hist_wt_kernel(const int* __restrict__ src,
                                                      const int* __restrict__ dst,
                                                      unsigned char* __restrict__ inpart,
                                                      unsigned char* __restrict__ outpart,
                                                      unsigned char* __restrict__ rank,
                                                      const float* __restrict__ W2,
                                                      const float* __restrict__ W3,
                                                      const float* __restrict__ W4,
                                                      _Float16* __restrict__ WT,
                                                      float* __restrict__ gacc) {
    __shared__ int h[PSZ + 4];                   // 12504 ints = 50016 B
    if (blockIdx.x >= NP * NS) {
        int wb = blockIdx.x - NP * NS;
        if (wb < 48) {                           // WT transpose: f32 [k][n] -> f16 [n][k]
            int i = wb * 256 + threadIdx.x;
            if (i < 3 * 4096) {
                int l = i >> 12;
                int r = i & 4095;
                int k = r >> 6, n = r & 63;
                const float* W = (l == 0) ? W2 : (l == 1) ? W3 : W4;
                WT[l * 4096 + n * 64 + k] = (_Float16)W[r];
            }
        } else {                                 // zero gacc[4096] + gcnt[64]
            for (int i = threadIdx.x; i < 64 * 64 + 64; i += 256) gacc[i] = 0.0f;
        }
        return;
    }
    int p = blockIdx.x / NS, s = blockIdx.x % NS;
    for (int i = threadIdx.x; i < (PSZ + 4) / 4; i += 256)
        ((int4*)h)[i] = make_int4(0, 0, 0, 0);
    __syncthreads();
    int lo = p * PSZ;
    int ebase = s * SSZ;
    const int4* d4 = (const int4*)(dst + ebase);
    const int4* s4 = (const int4*)(src + ebase);
    unsigned char* rk = rank + ebase;
    for (int i = threadIdx.x; i < SSZ / 4; i += 256) {
        int4 d = d4[i];
        int4 sv = s4[i];
        int t;
        t = d.x - lo;  if ((unsigned)t < PSZ) rk[4 * i + 0] = (unsigned char)(atomicAdd(&h[t], 1) & 0xffff);
        t = d.y - lo;  if ((unsigned)t < PSZ) rk[4 * i + 1] = (unsigned char)(atomicAdd(&h[t], 1) & 0xffff);
        t = d.z - lo;  if ((unsigned)t < PSZ) rk[4 * i + 2] = (unsigned char)(atomicAdd(&h[t], 1) & 0xffff);
        t = d.w - lo;  if ((unsigned)t < PSZ) rk[4 * i + 3] = (unsigned char)(atomicAdd(&h[t], 1) & 0xffff);
        t = sv.x - lo; if ((unsigned)t < PSZ) atomicAdd(&h[t], 0x10000);
        t = sv.y - lo; if ((unsigned)t < PSZ) atomicAdd(&h[t], 0x10000);
        t = sv.z - lo; if ((unsigned)t < PSZ) atomicAdd(&h[t], 0x10000);
        t = sv.w - lo; if ((unsigned)t < PSZ) atomicAdd(&h[t], 0x10000);
    }
    __syncthreads();
    unsigned char* ip = inpart + (size_t)s * N_NODES + lo;
    unsigned char* op = outpart + (size_t)s * N_NODES + lo;
    for (int i = threadIdx.x; i < PSZ / 2; i += 256) {
        int v0 = h[2 * i], v1 = h[2 * i + 1];
        uchar2 iv, ov;
        iv.x = (unsigned char)(v0 & 0xff);
        iv.y = (unsigned char)(v1 & 0xff);
        ov.x = (unsigned char)((v0 >> 16) & 0xff);
        ov.y = (unsigned char)((v1 >> 16) & 0xff);
        ((uchar2*)ip)[i] = iv;
        ((uchar2*)op)[i] = ov;
    }
}

// ---------------------------------------------------------------------------
// Fused: reduce u8 segment partials -> degrees AND rewrite inpart in place
// into the exclusive within-row segment prefix; features/norms (fp8 table);
// block scan; per-graph node counts.
// ---------------------------------------------------------------------------
__global__ void scan_block_feat_kernel(unsigned char* __restrict__ inpart,
                                       const unsigned char* __restrict__ outpart,
                                       const int* __restrict__ graph_ids,
                                       int* __restrict__ row_start, int* __restrict__ blk_sums,
                                       float* __restrict__ norm_src, float* __restrict__ norm_dst,
                                       uchar4* __restrict__ hs0, float* __restrict__ gcnt, int N) {
    __shared__ int ghist[64];
    if (threadIdx.x < 64) ghist[threadIdx.x] = 0;
    int i = blockIdx.x * 256 + threadIdx.x;
    int din_i = 0, dout_i = 0;
    if (i < N) {
        unsigned char run = 0;
#pragma unroll
        for (int s = 0; s < NS; ++s) {
            unsigned char c = inpart[(size_t)s * N_NODES + i];
            inpart[(size_t)s * N_NODES + i] = run;     // prefix rewrite in place
            run = (unsigned char)(run + c);
            dout_i += outpart[(size_t)s * N_NODES + i];
        }
        din_i = (int)run;
        float din = (float)din_i;
        float dout = (float)dout_i;
        float ns = 1.0f / sqrtf(fmaxf(dout, 1.0f));
        float nd = 1.0f / sqrtf(fmaxf(din, 1.0f));
        norm_src[i] = ns;
        norm_dst[i] = nd;
        float h1 = din;
        float h2 = (din - 3.0f > 0.0f) ? 1.0f : 0.0f;
        float h3 = 3.0f / din;
        float h4 = (din - 4.0f > 0.0f) ? 1.0f : 0.0f;
        uchar4 q;
        q.x = f_to_fp8(h1 * ns);
        q.y = f_to_fp8(h2 * ns);
        q.z = f_to_fp8(h3 * ns);
        q.w = f_to_fp8(h4 * ns);
        hs0[i] = q;
    }
    __syncthreads();
    if (i < N) atomicAdd(&ghist[graph_ids[i]], 1);
    int lane = threadIdx.x & 63;
    int wid = threadIdx.x >> 6;
    int x = din_i;
#pragma unroll
    for (int off = 1; off < 64; off <<= 1) {
        int t = __shfl_up(x, off);
        if (lane >= off) x += t;
    }
    __shared__ int wsum[4];
    if (lane == 63) wsum[wid] = x;
    __syncthreads();
    int woff = 0;
    for (int w = 0; w < wid; ++w) woff += wsum[w];
    int incl = x + woff;
    if (i < N) row_start[i] = incl - din_i;
    if (threadIdx.x == 255) blk_sums[blockIdx.x] = incl;
    if (threadIdx.x < 64 && ghist[threadIdx.x] > 0)
        atomicAdd(&gcnt[threadIdx.x], (float)ghist[threadIdx.x]);
}

// ---------------------------------------------------------------------------
// Slim: finalize row_start only (each block re-scans the 196 block sums).
// ---------------------------------------------------------------------------
__global__ void row_add_kernel(int* __restrict__ row_start,
                               const int* __restrict__ blk_sums, int N) {
    __shared__ int sOff[256];
    int t = threadIdx.x;
    int v = (t < NB) ? blk_sums[t] : 0;
    int lane = t & 63;
    int wid = t >> 6;
    int x = v;
#pragma unroll
    for (int off = 1; off < 64; off <<= 1) {
        int tt = __shfl_up(x, off);
        if (lane >= off) x += tt;
    }
    __shared__ int wsum[4];
    if (lane == 63) wsum[wid] = x;
    __syncthreads();
    int woff = 0;
    for (int w = 0; w < wid; ++w) woff += wsum[w];
    sOff[t] = x + woff - v;              // exclusive prefix of blk_sums
    __syncthreads();
    int i = blockIdx.x * 256 + threadIdx.x;
    if (blockIdx.x == 0 && threadIdx.x == 0) row_start[N] = N_EDGES;
    if (i < N) row_start[i] += sOff[blockIdx.x];
}

// ---------------------------------------------------------------------------
// Rank-based CSR fill: pos = row_start[d] + pref[s][d] + rank[e].
// csr_src is u16 (node ids < 50000 < 65536).
// ---------------------------------------------------------------------------
__global__ __launch_bounds__(256) void csr_fill_kernel(const int* __restrict__ src,
                                                       const int* __restrict__ dst,
                                                       const int* __restrict__ row_start,
                                                       const unsigned char* __restrict__ inpart,
                                                       const unsigned char* __restrict__ rank,
                                                       unsigned short* __restrict__ csr_src) {
    int i = blockIdx.x * 256 + threadIdx.x;          // edge-quad index
    if (i >= N_EDGES / 4) return;
    int4 d = ((const int4*)dst)[i];
    int4 sv = ((const int4*)src)[i];
    uchar4 rk = ((const uchar4*)rank)[i];
    int s = (4 * i) / SSZ;                           // uniform per SSZ/4 quads
    const unsigned char* pref = inpart + (size_t)s * N_NODES;
    csr_src[row_start[d.x] + (int)pref[d.x] + (int)rk.x] = (unsigned short)sv.x;
    csr_src[row_start[d.y] + (int)pref[d.y] + (int)rk.y] = (unsigned short)sv.y;
    csr_src[row_start[d.z] + (int)pref[d.z] + (int)rk.z] = (unsigned short)sv.z;
    csr_src[row_start[d.w] + (int)pref[d.w] + (int)rk.w] = (unsigned short)sv.w;
}

// ---------------------------------------------------------------------------
// Layer 1: IN=4 -> H=64. fp8x4 gather table (200 KB, L2-hot).
// ---------------------------------------------------------------------------
__global__ void conv4_kernel(const uchar4* __restrict__ hs0,
                             const int* __restrict__ row_start,
                             const unsigned short* __restrict__ csr_src,
                             const float* __restrict__ norm_src,
                             const float* __restrict__ norm_dst,
                             const float* __restrict__ W, const float* __restrict__ b,
                             unsigned char* __restrict__ out, int N) {
    __shared__ float sW[4 * 64];
    __shared__ float sb[64];
    sW[threadIdx.x] = W[threadIdx.x];
    if (threadIdx.x < 64) sb[threadIdx.x] = b[threadIdx.x];
    __syncthreads();
    int lane = threadIdx.x & 63;
    int wid = threadIdx.x >> 6;
    int v = blockIdx.x * 4 + wid;
    if (v >= N) return;
    int rs = row_start[v], re = row_start[v + 1];
    float ax = 0.f, ay = 0.f, az = 0.f, aw = 0.f;
    for (int e = rs + lane; e < re; e += 64) {
        uchar4 f = hs0[csr_src[e]];
        ax += fp8_to_f(f.x); ay += fp8_to_f(f.y);
        az += fp8_to_f(f.z); aw += fp8_to_f(f.w);
    }
#pragma unroll
    for (int off = 32; off; off >>= 1) {
        ax += __shfl_xor(ax, off);
        ay += __shfl_xor(ay, off);
        az += __shfl_xor(az, off);
        aw += __shfl_xor(aw, off);
    }
    float nd = norm_dst[v];
    float r = sb[lane] + nd * (ax * sW[lane] + ay * sW[64 + lane] +
                               az * sW[128 + lane] + aw * sW[192 + lane]);
    r = fmaxf(r, 0.0f) * norm_src[v];
    out[(size_t)v * 64 + lane] = f_to_fp8(r);
}

// ---------------------------------------------------------------------------
// Layers 2-4: H=64 -> H=64. R6 RESTRUCTURE: one node per 16-lane group.
//  * 4 nodes/wave, 16 nodes/block (grid 3125 x 256 thr).
//  * Gather: group's 16 lanes load dword hs_in[idx*64 + l16*4] — one VMEM
//    instr serves 4 rows (4 lines) across the 4 groups, all 64 lanes active.
//    ~250K VMEM/layer vs 850K before; 4 lines per vmcnt slot.
//  * No segmented scan: group == node, float4 acc IS the node aggregate
//    (same per-feature fp32 add order as before => bit-identical).
//  * Full 16-row MFMA (was 8 valid + 8 garbage); one 16-col slice per wave.
//  * One __syncthreads per block (sAgg crosses waves).
// ---------------------------------------------------------------------------
__global__ __launch_bounds__(256) void conv64_kernel(
        const unsigned char* __restrict__ hs_in,
        const int* __restrict__ row_start,
        const unsigned short* __restrict__ csr_src,
        const float* __restrict__ norm_src,
        const float* __restrict__ norm_dst,
        const _Float16* __restrict__ WT, const float* __restrict__ b,
        unsigned char* __restrict__ out8,
        const int* __restrict__ graph_ids, float* __restrict__ gacc,
        int do_pool, int N) {
    __shared__ _Float16 sAgg[16][72];
    const int lane = threadIdx.x & 63;
    const int wavei = __builtin_amdgcn_readfirstlane(threadIdx.x >> 6);
    const int l16 = lane & 15;
    const int gsel = (lane >> 4);                 // group 0..3
    const int vblock = blockIdx.x * 16;           // 50000 = 3125*16 exactly
    const int node = vblock + wavei * 4 + gsel;

    const int rs = row_start[node];               // group-uniform
    const int deg = row_start[node + 1] - rs;

    // wave-max chunk count (16 edges/chunk)
    int ncg = (deg + 15) >> 4;
    int m1 = max(ncg, __shfl_xor(ncg, 16));
    int ncw = max(m1, __shfl_xor(m1, 32));

    float acc0 = 0.f, acc1 = 0.f, acc2 = 0.f, acc3 = 0.f;
    const int blane = (lane & 48);                // group base lane * 1

    int pos = rs + l16;                           // my slot in chunk 0
    unsigned pc = (unsigned)pos;
    if (pc > (unsigned)(N_EDGES - 1)) pc = N_EDGES - 1;
    int idx = (int)csr_src[pc];

    for (int c = 0; c < ncw; ++c) {
        // prefetch next chunk's indices
        int posN = rs + (c + 1) * 16 + l16;
        unsigned pn = (unsigned)posN;
        if (pn > (unsigned)(N_EDGES - 1)) pn = N_EDGES - 1;
        int idxN = (int)csr_src[pn];

        // issue 16 gathers (one per edge slot; 4 groups share each instr)
        unsigned tv0, tv1, tv2, tv3, tv4, tv5, tv6, tv7;
        unsigned tv8, tv9, tv10, tv11, tv12, tv13, tv14, tv15;
#define GLOAD(J, TV)                                                        \
        {                                                                   \
            int si = __shfl(idx, blane + (J));                              \
            TV = *(const unsigned*)(hs_in + (((size_t)(unsigned)si) << 6)   \
                                    + (l16 << 2));                          \
        }
        GLOAD(0, tv0)   GLOAD(1, tv1)   GLOAD(2, tv2)   GLOAD(3, tv3)
        GLOAD(4, tv4)   GLOAD(5, tv5)   GLOAD(6, tv6)   GLOAD(7, tv7)
        GLOAD(8, tv8)   GLOAD(9, tv9)   GLOAD(10, tv10) GLOAD(11, tv11)
        GLOAD(12, tv12) GLOAD(13, tv13) GLOAD(14, tv14) GLOAD(15, tv15)
#undef GLOAD
        int cbase = c * 16;
#define ACC(J, TV)                                                          \
        {                                                                   \
            float mk = (cbase + (J) < deg) ? 1.0f : 0.0f;                   \
            acc0 += mk * fp8_to_f((unsigned char)(TV & 0xff));              \
            acc1 += mk * fp8_to_f((unsigned char)((TV >> 8) & 0xff));       \
            acc2 += mk * fp8_to_f((unsigned char)((TV >> 16) & 0xff));      \
            acc3 += mk * fp8_to_f((unsigned char)((TV >> 24) & 0xff));      \
        }
        ACC(0, tv0)   ACC(1, tv1)   ACC(2, tv2)   ACC(3, tv3)
        ACC(4, tv4)   ACC(5, tv5)   ACC(6, tv6)   ACC(7, tv7)
        ACC(8, tv8)   ACC(9, tv9)   ACC(10, tv10) ACC(11, tv11)
        ACC(12, tv12) ACC(13, tv13) ACC(14, tv14) ACC(15, tv15)
#undef ACC
        idx = idxN;
    }

    // flush: scale by norm_dst, write 4 f16 (8B) to this node's sAgg row
    float nd = norm_dst[node];
    _Float16 f0 = (_Float16)(acc0 * nd);
    _Float16 f1 = (_Float16)(acc1 * nd);
    _Float16 f2 = (_Float16)(acc2 * nd);
    _Float16 f3 = (_Float16)(acc3 * nd);
    _Float16* rowp = &sAgg[wavei * 4 + gsel][l16 * 4];
    rowp[0] = f0; rowp[1] = f1; rowp[2] = f2; rowp[3] = f3;
    __syncthreads();

    // MFMA: A = sAgg[16][64] (16 valid nodes); each wave does one 16-col slice
    const int l15 = lane & 15;
    const int quad = lane >> 4;
    const _Float16* aRow = &sAgg[l15][quad * 8];
    half8 a0 = *(const half8*)(aRow);
    half8 a1 = *(const half8*)(aRow + 32);

    const _Float16* bp = WT + ((size_t)(wavei * 16 + l15)) * 64 + quad * 8;
    half8 b0 = *(const half8*)bp;
    half8 b1 = *(const half8*)(bp + 32);

    floatx4 cc = (floatx4){0.f, 0.f, 0.f, 0.f};
    cc = __builtin_amdgcn_mfma_f32_16x16x32_f16(a0, b0, cc, 0, 0, 0);
    cc = __builtin_amdgcn_mfma_f32_16x16x32_f16(a1, b1, cc, 0, 0, 0);

    const int col = wavei * 16 + l15;
    float bias = b[col];

    if (do_pool) {
        int g0 = graph_ids[vblock];                // wave-uniform s_loads
        int g15 = graph_ids[vblock + 15];
        if (g0 == g15) {
            // fast path: all 16 nodes in one graph
            float fsum = 0.0f;
#pragma unroll
            for (int r = 0; r < 4; ++r)
                fsum += fmaxf(cc[r] + bias, 0.0f);
            fsum += __shfl_xor(fsum, 16);
            fsum += __shfl_xor(fsum, 32);
            if (quad == 0)
                atomicAdd(&gacc[g0 * 64 + col], fsum);
        } else {
            // graph boundary (~1% of blocks): per-node atomics
#pragma unroll
            for (int r = 0; r < 4; ++r) {
                int m = quad * 4 + r;
                float val = fmaxf(cc[r] + bias, 0.0f);
                atomicAdd(&gacc[graph_ids[vblock + m] * 64 + col], val);
            }
        }
    } else {
#pragma unroll
        for (int r = 0; r < 4; ++r) {
            int m = quad * 4 + r;
            int v = vblock + m;
            float val = fmaxf(cc[r] + bias, 0.0f) * norm_src[v];
            out8[(size_t)v * 64 + col] = f_to_fp8(val);
        }
    }
}

// ---------------------------------------------------------------------------
// Pool stage 2: one wave per graph (16 blocks x 4 waves).
// ---------------------------------------------------------------------------
__global__ void pool2_kernel(const float* __restrict__ gacc, const float* __restrict__ gcnt,
                             const float* __restrict__ Wout, const float* __restrict__ bout,
                             float* __restrict__ out) {
    int lane = threadIdx.x & 63;
    int g = blockIdx.x * 4 + (threadIdx.x >> 6);   // 64 waves total
    float p = (gacc[g * 64 + lane] / gcnt[g]) * Wout[lane];
#pragma unroll
    for (int off = 32; off; off >>= 1) p += __shfl_xor(p, off);
    if (lane == 0) out[g] = 1.0f / (1.0f + expf(-(p + bout[0])));
}

// ---------------------------------------------------------------------------
extern "C" void kernel_launch(void* const* d_in, const int* in_sizes, int n_in,
                              void* d_out, int out_size, void* d_ws, size_t ws_size,
                              hipStream_t stream) {
    const int* src = (const int*)d_in[0];
    const int* dst = (const int*)d_in[1];
    const int* graph_ids = (const int*)d_in[2];
    const float* W1 = (const float*)d_in[3];
    const float* b1 = (const float*)d_in[4];
    const float* W2 = (const float*)d_in[5];
    const float* b2 = (const float*)d_in[6];
    const float* W3 = (const float*)d_in[7];
    const float* b3 = (const float*)d_in[8];
    const float* W4 = (const float*)d_in[9];
    const float* b4 = (const float*)d_in[10];
    const float* Wout = (const float*)d_in[11];
    const float* bout = (const float*)d_in[12];
    float* out = (float*)d_out;

    const int N = N_NODES, E = N_EDGES;

    unsigned char* buf8A = (unsigned char*)d_ws;           // N*64 fp8
    unsigned char* buf8B = buf8A + (size_t)N * 64;         // N*64 fp8
    _Float16* WT   = (_Float16*)(buf8B + (size_t)N * 64);  // 3*4096 f16
    float* gacc = (float*)(WT + 3 * 4096);                 // 64*64 f32
    float* gcnt = gacc + 64 * 64;                          // 64 f32
    unsigned char* hs0 = (unsigned char*)(gcnt + 64);      // N*4 fp8 (4B-aligned)
    float* norm_src = (float*)(hs0 + (size_t)N * 4);       // N
    float* norm_dst = norm_src + N;                        // N
    unsigned short* csr_src = (unsigned short*)(norm_dst + N);   // E u16
    int* row_start = (int*)(csr_src + E);                  // N+1
    int* blk_sums  = row_start + (N + 1);                  // NB
    unsigned char* inpart  = (unsigned char*)(blk_sums + NB + 1);    // NS*N u8
    unsigned char* outpart = inpart + (size_t)NS * N;                // NS*N u8
    unsigned char* rank    = outpart + (size_t)NS * N;               // E u8

    // hist (256) + WT transpose (48) + gacc/gcnt zero (1)
    hist_wt_kernel<<<NP * NS + 49, 256, 0, stream>>>(src, dst, inpart, outpart, rank,
                                                     W2, W3, W4, WT, gacc);
    scan_block_feat_kernel<<<NB, 256, 0, stream>>>(inpart, outpart, graph_ids,
                                                   row_start, blk_sums,
                                                   norm_src, norm_dst, (uchar4*)hs0, gcnt, N);
    row_add_kernel<<<NB, 256, 0, stream>>>(row_start, blk_sums, N);
    csr_fill_kernel<<<(E / 4 + 255) / 256, 256, 0, stream>>>(src, dst, row_start, inpart,
                                                             rank, csr_src);

    conv4_kernel<<<(N + 3) / 4, 256, 0, stream>>>((const uchar4*)hs0, row_start, csr_src,
                                                  norm_src, norm_dst, W1, b1, buf8A, N);
    const int CB = N / 16;          // 16 nodes/block (4 waves x 4 nodes)
    conv64_kernel<<<CB, 256, 0, stream>>>(buf8A, row_start, csr_src, norm_src, norm_dst,
                                          WT + 0 * 4096, b2, buf8B, graph_ids, gacc, 0, N);
    conv64_kernel<<<CB, 256, 0, stream>>>(buf8B, row_start, csr_src, norm_src, norm_dst,
                                          WT + 1 * 4096, b3, buf8A, graph_ids, gacc, 0, N);
    conv64_kernel<<<CB, 256, 0, stream>>>(buf8A, row_start, csr_src, norm_src, norm_dst,
                                          WT + 2 * 4096, b4, (unsigned char*)nullptr,
                                          graph_ids, gacc, 1, N);

    pool2_kernel<<<16, 256, 0, stream>>>(gacc, gcnt, Wout, bout, out);
}

// Round 7
// 184.270 us; speedup vs baseline: 1.2498x; 1.0531x over previous
//
#include <hip/hip_runtime.h>
#include <hip/hip_fp8.h>
#include <math.h>

#define N_NODES 50000
#define N_EDGES 800000
#define NP 4                      // node partitions (12500 nodes each)
#define NS 64                     // edge segments (12500 edges each)
#define PSZ (N_NODES / NP)        // 12500
#define SSZ (N_EDGES / NS)        // 12500
#define NB 196                    // ceil(N/256)

typedef _Float16 half8 __attribute__((ext_vector_type(8)));
typedef float floatx4 __attribute__((ext_vector_type(4)));

// ---------------- fp8 e4m3 (OCP) helpers — HW cvt on gfx950 ----------------
__device__ __forceinline__ unsigned char f_to_fp8(float f) {
    __hip_fp8_e4m3 q(f);
    return (unsigned char)q.__x;
}
__device__ __forceinline__ float fp8_to_f(unsigned char u) {
    __hip_fp8_e4m3 q;
    q.__x = (__hip_fp8_storage_t)u;
    return (float)q;
}

// ---------------------------------------------------------------------------
// Fused: partitioned LDS histogram (blocks 0..NP*NS-1) + WT transpose +
// gacc/gcnt zeroing. Packed u32 counters (in low16 / out high16); the
// atomicAdd return's low bits are the edge's within-segment rank (u8).
// ---------------------------------------------------------------------------
__global__ __launch_bounds__(256) void hist_wt_kernel(const int* __restrict__ src,
                                                      const int* __restrict__ dst,
                                                      unsigned char* __restrict__ inpart,
                                                      unsigned char* __restrict__ outpart,
                                                      unsigned char* __restrict__ rank,
                                                      const float* __restrict__ W2,
                                                      const float* __restrict__ W3,
                                                      const float* __restrict__ W4,
                                                      _Float16* __restrict__ WT,
                                                      float* __restrict__ gacc) {
    __shared__ int h[PSZ + 4];                   // 12504 ints = 50016 B
    if (blockIdx.x >= NP * NS) {
        int wb = blockIdx.x - NP * NS;
        if (wb < 48) {                           // WT transpose: f32 [k][n] -> f16 [n][k]
            int i = wb * 256 + threadIdx.x;
            if (i < 3 * 4096) {
                int l = i >> 12;
                int r = i & 4095;
                int k = r >> 6, n = r & 63;
                const float* W = (l == 0) ? W2 : (l == 1) ? W3 : W4;
                WT[l * 4096 + n * 64 + k] = (_Float16)W[r];
            }
        } else {                                 // zero gacc[4096] + gcnt[64]
            for (int i = threadIdx.x; i < 64 * 64 + 64; i += 256) gacc[i] = 0.0f;
        }
        return;
    }
    int p = blockIdx.x / NS, s = blockIdx.x % NS;
    for (int i = threadIdx.x; i < (PSZ + 4) / 4; i += 256)
        ((int4*)h)[i] = make_int4(0, 0, 0, 0);
    __syncthreads();
    int lo = p * PSZ;
    int ebase = s * SSZ;
    const int4* d4 = (const int4*)(dst + ebase);
    const int4* s4 = (const int4*)(src + ebase);
    unsigned char* rk = rank + ebase;
    for (int i = threadIdx.x; i < SSZ / 4; i += 256) {
        int4 d = d4[i];
        int4 sv = s4[i];
        int t;
        t = d.x - lo;  if ((unsigned)t < PSZ) rk[4 * i + 0] = (unsigned char)(atomicAdd(&h[t], 1) & 0xffff);
        t = d.y - lo;  if ((unsigned)t < PSZ) rk[4 * i + 1] = (unsigned char)(atomicAdd(&h[t], 1) & 0xffff);
        t = d.z - lo;  if ((unsigned)t < PSZ) rk[4 * i + 2] = (unsigned char)(atomicAdd(&h[t], 1) & 0xffff);
        t = d.w - lo;  if ((unsigned)t < PSZ) rk[4 * i + 3] = (unsigned char)(atomicAdd(&h[t], 1) & 0xffff);
        t = sv.x - lo; if ((unsigned)t < PSZ) atomicAdd(&h[t], 0x10000);
        t = sv.y - lo; if ((unsigned)t < PSZ) atomicAdd(&h[t], 0x10000);
        t = sv.z - lo; if ((unsigned)t < PSZ) atomicAdd(&h[t], 0x10000);
        t = sv.w - lo; if ((unsigned)t < PSZ) atomicAdd(&h[t], 0x10000);
    }
    __syncthreads();
    unsigned char* ip = inpart + (size_t)s * N_NODES + lo;
    unsigned char* op = outpart + (size_t)s * N_NODES + lo;
    for (int i = threadIdx.x; i < PSZ / 2; i += 256) {
        int v0 = h[2 * i], v1 = h[2 * i + 1];
        uchar2 iv, ov;
        iv.x = (unsigned char)(v0 & 0xff);
        iv.y = (unsigned char)(v1 & 0xff);
        ov.x = (unsigned char)((v0 >> 16) & 0xff);
        ov.y = (unsigned char)((v1 >> 16) & 0xff);
        ((uchar2*)ip)[i] = iv;
        ((uchar2*)op)[i] = ov;
    }
}

// ---------------------------------------------------------------------------
// Fused: reduce u8 segment partials -> degrees AND rewrite inpart in place
// into the exclusive within-row segment prefix; features/norms (fp8 table);
// block scan; per-graph node counts.
// ---------------------------------------------------------------------------
__global__ void scan_block_feat_kernel(unsigned char* __restrict__ inpart,
                                       const unsigned char* __restrict__ outpart,
                                       const int* __restrict__ graph_ids,
                                       int* __restrict__ row_start, int* __restrict__ blk_sums,
                                       float* __restrict__ norm_src, float* __restrict__ norm_dst,
                                       uchar4* __restrict__ hs0, float* __restrict__ gcnt, int N) {
    __shared__ int ghist[64];
    if (threadIdx.x < 64) ghist[threadIdx.x] = 0;
    int i = blockIdx.x * 256 + threadIdx.x;
    int din_i = 0, dout_i = 0;
    if (i < N) {
        unsigned char run = 0;
#pragma unroll
        for (int s = 0; s < NS; ++s) {
            unsigned char c = inpart[(size_t)s * N_NODES + i];
            inpart[(size_t)s * N_NODES + i] = run;     // prefix rewrite in place
            run = (unsigned char)(run + c);
            dout_i += outpart[(size_t)s * N_NODES + i];
        }
        din_i = (int)run;
        float din = (float)din_i;
        float dout = (float)dout_i;
        float ns = 1.0f / sqrtf(fmaxf(dout, 1.0f));
        float nd = 1.0f / sqrtf(fmaxf(din, 1.0f));
        norm_src[i] = ns;
        norm_dst[i] = nd;
        float h1 = din;
        float h2 = (din - 3.0f > 0.0f) ? 1.0f : 0.0f;
        float h3 = 3.0f / din;
        float h4 = (din - 4.0f > 0.0f) ? 1.0f : 0.0f;
        uchar4 q;
        q.x = f_to_fp8(h1 * ns);
        q.y = f_to_fp8(h2 * ns);
        q.z = f_to_fp8(h3 * ns);
        q.w = f_to_fp8(h4 * ns);
        hs0[i] = q;
    }
    __syncthreads();
    if (i < N) atomicAdd(&ghist[graph_ids[i]], 1);
    int lane = threadIdx.x & 63;
    int wid = threadIdx.x >> 6;
    int x = din_i;
#pragma unroll
    for (int off = 1; off < 64; off <<= 1) {
        int t = __shfl_up(x, off);
        if (lane >= off) x += t;
    }
    __shared__ int wsum[4];
    if (lane == 63) wsum[wid] = x;
    __syncthreads();
    int woff = 0;
    for (int w = 0; w < wid; ++w) woff += wsum[w];
    int incl = x + woff;
    if (i < N) row_start[i] = incl - din_i;
    if (threadIdx.x == 255) blk_sums[blockIdx.x] = incl;
    if (threadIdx.x < 64 && ghist[threadIdx.x] > 0)
        atomicAdd(&gcnt[threadIdx.x], (float)ghist[threadIdx.x]);
}

// ---------------------------------------------------------------------------
// Slim: finalize row_start only (each block re-scans the 196 block sums).
// ---------------------------------------------------------------------------
__global__ void row_add_kernel(int* __restrict__ row_start,
                               const int* __restrict__ blk_sums, int N) {
    __shared__ int sOff[256];
    int t = threadIdx.x;
    int v = (t < NB) ? blk_sums[t] : 0;
    int lane = t & 63;
    int wid = t >> 6;
    int x = v;
#pragma unroll
    for (int off = 1; off < 64; off <<= 1) {
        int tt = __shfl_up(x, off);
        if (lane >= off) x += tt;
    }
    __shared__ int wsum[4];
    if (lane == 63) wsum[wid] = x;
    __syncthreads();
    int woff = 0;
    for (int w = 0; w < wid; ++w) woff += wsum[w];
    sOff[t] = x + woff - v;              // exclusive prefix of blk_sums
    __syncthreads();
    int i = blockIdx.x * 256 + threadIdx.x;
    if (blockIdx.x == 0 && threadIdx.x == 0) row_start[N] = N_EDGES;
    if (i < N) row_start[i] += sOff[blockIdx.x];
}

// ---------------------------------------------------------------------------
// Rank-based CSR fill: pos = row_start[d] + pref[s][d] + rank[e].
// csr_src is u16 (node ids < 50000 < 65536).
// ---------------------------------------------------------------------------
__global__ __launch_bounds__(256) void csr_fill_kernel(const int* __restrict__ src,
                                                       const int* __restrict__ dst,
                                                       const int* __restrict__ row_start,
                                                       const unsigned char* __restrict__ inpart,
                                                       const unsigned char* __restrict__ rank,
                                                       unsigned short* __restrict__ csr_src) {
    int i = blockIdx.x * 256 + threadIdx.x;          // edge-quad index
    if (i >= N_EDGES / 4) return;
    int4 d = ((const int4*)dst)[i];
    int4 sv = ((const int4*)src)[i];
    uchar4 rk = ((const uchar4*)rank)[i];
    int s = (4 * i) / SSZ;                           // uniform per SSZ/4 quads
    const unsigned char* pref = inpart + (size_t)s * N_NODES;
    csr_src[row_start[d.x] + (int)pref[d.x] + (int)rk.x] = (unsigned short)sv.x;
    csr_src[row_start[d.y] + (int)pref[d.y] + (int)rk.y] = (unsigned short)sv.y;
    csr_src[row_start[d.z] + (int)pref[d.z] + (int)rk.z] = (unsigned short)sv.z;
    csr_src[row_start[d.w] + (int)pref[d.w] + (int)rk.w] = (unsigned short)sv.w;
}

// ---------------------------------------------------------------------------
// Layer 1: IN=4 -> H=64. R7: same 16-lane-group structure as conv64.
//  * 4 nodes/wave, 16 nodes/block (grid 3125 x 256 thr) — was 1 node/wave
//    with ~75% idle lanes at avg deg 16.
//  * Each lane gathers one edge's uchar4 (all 64 lanes active); group-local
//    shfl_xor reduce; each lane emits 4 output features as one coalesced
//    uchar4 store (64 B per group).
// ---------------------------------------------------------------------------
__global__ __launch_bounds__(256) void conv4_kernel(const unsigned char* __restrict__ hs0,
                                                    const int* __restrict__ row_start,
                                                    const unsigned short* __restrict__ csr_src,
                                                    const float* __restrict__ norm_src,
                                                    const float* __restrict__ norm_dst,
                                                    const float* __restrict__ W,
                                                    const float* __restrict__ b,
                                                    unsigned char* __restrict__ out, int N) {
    __shared__ float sW[4 * 64];
    __shared__ float sb[64];
    sW[threadIdx.x] = W[threadIdx.x];
    if (threadIdx.x < 64) sb[threadIdx.x] = b[threadIdx.x];

    const int lane = threadIdx.x & 63;
    const int wavei = threadIdx.x >> 6;
    const int l16 = lane & 15;
    const int node = blockIdx.x * 16 + wavei * 4 + (lane >> 4);   // 3125*16 = N

    const int rs = row_start[node];                 // group-uniform
    const int deg = row_start[node + 1] - rs;
    const int ncg = (deg + 15) >> 4;

    float a0 = 0.f, a1 = 0.f, a2 = 0.f, a3 = 0.f;
    for (int c = 0; c < ncg; ++c) {                 // group-divergent, exec-masked
        int off = c * 16 + l16;
        unsigned pos = (unsigned)(rs + off);
        if (pos > (unsigned)(N_EDGES - 1)) pos = N_EDGES - 1;
        unsigned idx = csr_src[pos];
        unsigned tv = *(const unsigned*)(hs0 + ((size_t)idx << 2));
        if (off >= deg) tv = 0u;                    // fp8 0x00 == 0.0f
        a0 += fp8_to_f((unsigned char)(tv & 0xff));
        a1 += fp8_to_f((unsigned char)((tv >> 8) & 0xff));
        a2 += fp8_to_f((unsigned char)((tv >> 16) & 0xff));
        a3 += fp8_to_f((unsigned char)((tv >> 24) & 0xff));
    }
#pragma unroll
    for (int o = 1; o < 16; o <<= 1) {              // reduce within 16-lane group
        a0 += __shfl_xor(a0, o);
        a1 += __shfl_xor(a1, o);
        a2 += __shfl_xor(a2, o);
        a3 += __shfl_xor(a3, o);
    }
    __syncthreads();                                // sW/sb ready
    float nd = norm_dst[node];
    float ns = norm_src[node];
    uchar4 q;
    unsigned char* qp = (unsigned char*)&q;
#pragma unroll
    for (int j = 0; j < 4; ++j) {
        int f = l16 * 4 + j;
        float r = sb[f] + nd * (a0 * sW[f] + a1 * sW[64 + f] +
                                a2 * sW[128 + f] + a3 * sW[192 + f]);
        qp[j] = f_to_fp8(fmaxf(r, 0.0f) * ns);
    }
    *(uchar4*)(out + (size_t)node * 64 + l16 * 4) = q;
}

// ---------------------------------------------------------------------------
// Layers 2-4: H=64 -> H=64. R6 structure (one node per 16-lane group).
// ---------------------------------------------------------------------------
__global__ __launch_bounds__(256) void conv64_kernel(
        const unsigned char* __restrict__ hs_in,
        const int* __restrict__ row_start,
        const unsigned short* __restrict__ csr_src,
        const float* __restrict__ norm_src,
        const float* __restrict__ norm_dst,
        const _Float16* __restrict__ WT, const float* __restrict__ b,
        unsigned char* __restrict__ out8,
        const int* __restrict__ graph_ids, float* __restrict__ gacc,
        int do_pool, int N) {
    __shared__ _Float16 sAgg[16][72];
    const int lane = threadIdx.x & 63;
    const int wavei = __builtin_amdgcn_readfirstlane(threadIdx.x >> 6);
    const int l16 = lane & 15;
    const int gsel = (lane >> 4);                 // group 0..3
    const int vblock = blockIdx.x * 16;           // 50000 = 3125*16 exactly
    const int node = vblock + wavei * 4 + gsel;

    const int rs = row_start[node];               // group-uniform
    const int deg = row_start[node + 1] - rs;

    // wave-max chunk count (16 edges/chunk)
    int ncg = (deg + 15) >> 4;
    int m1 = max(ncg, __shfl_xor(ncg, 16));
    int ncw = max(m1, __shfl_xor(m1, 32));

    float acc0 = 0.f, acc1 = 0.f, acc2 = 0.f, acc3 = 0.f;
    const int blane = (lane & 48);                // group base lane

    int pos = rs + l16;                           // my slot in chunk 0
    unsigned pc = (unsigned)pos;
    if (pc > (unsigned)(N_EDGES - 1)) pc = N_EDGES - 1;
    int idx = (int)csr_src[pc];

    for (int c = 0; c < ncw; ++c) {
        // prefetch next chunk's indices
        int posN = rs + (c + 1) * 16 + l16;
        unsigned pn = (unsigned)posN;
        if (pn > (unsigned)(N_EDGES - 1)) pn = N_EDGES - 1;
        int idxN = (int)csr_src[pn];

        // issue 16 gathers (one per edge slot; 4 groups share each instr)
        unsigned tv0, tv1, tv2, tv3, tv4, tv5, tv6, tv7;
        unsigned tv8, tv9, tv10, tv11, tv12, tv13, tv14, tv15;
#define GLOAD(J, TV)                                                        \
        {                                                                   \
            int si = __shfl(idx, blane + (J));                              \
            TV = *(const unsigned*)(hs_in + (((size_t)(unsigned)si) << 6)   \
                                    + (l16 << 2));                          \
        }
        GLOAD(0, tv0)   GLOAD(1, tv1)   GLOAD(2, tv2)   GLOAD(3, tv3)
        GLOAD(4, tv4)   GLOAD(5, tv5)   GLOAD(6, tv6)   GLOAD(7, tv7)
        GLOAD(8, tv8)   GLOAD(9, tv9)   GLOAD(10, tv10) GLOAD(11, tv11)
        GLOAD(12, tv12) GLOAD(13, tv13) GLOAD(14, tv14) GLOAD(15, tv15)
#undef GLOAD
        int cbase = c * 16;
#define ACC(J, TV)                                                          \
        {                                                                   \
            float mk = (cbase + (J) < deg) ? 1.0f : 0.0f;                   \
            acc0 += mk * fp8_to_f((unsigned char)(TV & 0xff));              \
            acc1 += mk * fp8_to_f((unsigned char)((TV >> 8) & 0xff));       \
            acc2 += mk * fp8_to_f((unsigned char)((TV >> 16) & 0xff));      \
            acc3 += mk * fp8_to_f((unsigned char)((TV >> 24) & 0xff));      \
        }
        ACC(0, tv0)   ACC(1, tv1)   ACC(2, tv2)   ACC(3, tv3)
        ACC(4, tv4)   ACC(5, tv5)   ACC(6, tv6)   ACC(7, tv7)
        ACC(8, tv8)   ACC(9, tv9)   ACC(10, tv10) ACC(11, tv11)
        ACC(12, tv12) ACC(13, tv13) ACC(14, tv14) ACC(15, tv15)
#undef ACC
        idx = idxN;
    }

    // flush: scale by norm_dst, write 4 f16 (8B) to this node's sAgg row
    float nd = norm_dst[node];
    _Float16 f0 = (_Float16)(acc0 * nd);
    _Float16 f1 = (_Float16)(acc1 * nd);
    _Float16 f2 = (_Float16)(acc2 * nd);
    _Float16 f3 = (_Float16)(acc3 * nd);
    _Float16* rowp = &sAgg[wavei * 4 + gsel][l16 * 4];
    rowp[0] = f0; rowp[1] = f1; rowp[2] = f2; rowp[3] = f3;
    __syncthreads();

    // MFMA: A = sAgg[16][64] (16 valid nodes); each wave does one 16-col slice
    const int l15 = lane & 15;
    const int quad = lane >> 4;
    const _Float16* aRow = &sAgg[l15][quad * 8];
    half8 a0 = *(const half8*)(aRow);
    half8 a1 = *(const half8*)(aRow + 32);

    const _Float16* bp = WT + ((size_t)(wavei * 16 + l15)) * 64 + quad * 8;
    half8 b0 = *(const half8*)bp;
    half8 b1 = *(const half8*)(bp + 32);

    floatx4 cc = (floatx4){0.f, 0.f, 0.f, 0.f};
    cc = __builtin_amdgcn_mfma_f32_16x16x32_f16(a0, b0, cc, 0, 0, 0);
    cc = __builtin_amdgcn_mfma_f32_16x16x32_f16(a1, b1, cc, 0, 0, 0);

    const int col = wavei * 16 + l15;
    float bias = b[col];

    if (do_pool) {
        int g0 = graph_ids[vblock];                // wave-uniform s_loads
        int g15 = graph_ids[vblock + 15];
        if (g0 == g15) {
            // fast path: all 16 nodes in one graph
            float fsum = 0.0f;
#pragma unroll
            for (int r = 0; r < 4; ++r)
                fsum += fmaxf(cc[r] + bias, 0.0f);
            fsum += __shfl_xor(fsum, 16);
            fsum += __shfl_xor(fsum, 32);
            if (quad == 0)
                atomicAdd(&gacc[g0 * 64 + col], fsum);
        } else {
            // graph boundary (~1% of blocks): per-node atomics
#pragma unroll
            for (int r = 0; r < 4; ++r) {
                int m = quad * 4 + r;
                float val = fmaxf(cc[r] + bias, 0.0f);
                atomicAdd(&gacc[graph_ids[vblock + m] * 64 + col], val);
            }
        }
    } else {
#pragma unroll
        for (int r = 0; r < 4; ++r) {
            int m = quad * 4 + r;
            int v = vblock + m;
            float val = fmaxf(cc[r] + bias, 0.0f) * norm_src[v];
            out8[(size_t)v * 64 + col] = f_to_fp8(val);
        }
    }
}

// ---------------------------------------------------------------------------
// Pool stage 2: one wave per graph (16 blocks x 4 waves).
// ---------------------------------------------------------------------------
__global__ void pool2_kernel(const float* __restrict__ gacc, const float* __restrict__ gcnt,
                             const float* __restrict__ Wout, const float* __restrict__ bout,
                             float* __restrict__ out) {
    int lane = threadIdx.x & 63;
    int g = blockIdx.x * 4 + (threadIdx.x >> 6);   // 64 waves total
    float p = (gacc[g * 64 + lane] / gcnt[g]) * Wout[lane];
#pragma unroll
    for (int off = 32; off; off >>= 1) p += __shfl_xor(p, off);
    if (lane == 0) out[g] = 1.0f / (1.0f + expf(-(p + bout[0])));
}

// ---------------------------------------------------------------------------
extern "C" void kernel_launch(void* const* d_in, const int* in_sizes, int n_in,
                              void* d_out, int out_size, void* d_ws, size_t ws_size,
                              hipStream_t stream) {
    const int* src = (const int*)d_in[0];
    const int* dst = (const int*)d_in[1];
    const int* graph_ids = (const int*)d_in[2];
    const float* W1 = (const float*)d_in[3];
    const float* b1 = (const float*)d_in[4];
    const float* W2 = (const float*)d_in[5];
    const float* b2 = (const float*)d_in[6];
    const float* W3 = (const float*)d_in[7];
    const float* b3 = (const float*)d_in[8];
    const float* W4 = (const float*)d_in[9];
    const float* b4 = (const float*)d_in[10];
    const float* Wout = (const float*)d_in[11];
    const float* bout = (const float*)d_in[12];
    float* out = (float*)d_out;

    const int N = N_NODES, E = N_EDGES;

    unsigned char* buf8A = (unsigned char*)d_ws;           // N*64 fp8
    unsigned char* buf8B = buf8A + (size_t)N * 64;         // N*64 fp8
    _Float16* WT   = (_Float16*)(buf8B + (size_t)N * 64);  // 3*4096 f16
    float* gacc = (float*)(WT + 3 * 4096);                 // 64*64 f32
    float* gcnt = gacc + 64 * 64;                          // 64 f32
    unsigned char* hs0 = (unsigned char*)(gcnt + 64);      // N*4 fp8 (4B-aligned)
    float* norm_src = (float*)(hs0 + (size_t)N * 4);       // N
    float* norm_dst = norm_src + N;                        // N
    unsigned short* csr_src = (unsigned short*)(norm_dst + N);   // E u16
    int* row_start = (int*)(csr_src + E);                  // N+1
    int* blk_sums  = row_start + (N + 1);                  // NB
    unsigned char* inpart  = (unsigned char*)(blk_sums + NB + 1);    // NS*N u8
    unsigned char* outpart = inpart + (size_t)NS * N;                // NS*N u8
    unsigned char* rank    = outpart + (size_t)NS * N;               // E u8

    // hist (256) + WT transpose (48) + gacc/gcnt zero (1)
    hist_wt_kernel<<<NP * NS + 49, 256, 0, stream>>>(src, dst, inpart, outpart, rank,
                                                     W2, W3, W4, WT, gacc);
    scan_block_feat_kernel<<<NB, 256, 0, stream>>>(inpart, outpart, graph_ids,
                                                   row_start, blk_sums,
                                                   norm_src, norm_dst, (uchar4*)hs0, gcnt, N);
    row_add_kernel<<<NB, 256, 0, stream>>>(row_start, blk_sums, N);
    csr_fill_kernel<<<(E / 4 + 255) / 256, 256, 0, stream>>>(src, dst, row_start, inpart,
                                                             rank, csr_src);

    const int CB = N / 16;          // 16 nodes/block (4 waves x 4 nodes)
    conv4_kernel<<<CB, 256, 0, stream>>>(hs0, row_start, csr_src,
                                         norm_src, norm_dst, W1, b1, buf8A, N);
    conv64_kernel<<<CB, 256, 0, stream>>>(buf8A, row_start, csr_src, norm_src, norm_dst,
                                          WT + 0 * 4096, b2, buf8B, graph_ids, gacc, 0, N);
    conv64_kernel<<<CB, 256, 0, stream>>>(buf8B, row_start, csr_src, norm_src, norm_dst,
                                          WT + 1 * 4096, b3, buf8A, graph_ids, gacc, 0, N);
    conv64_kernel<<<CB, 256, 0, stream>>>(buf8A, row_start, csr_src, norm_src, norm_dst,
                                          WT + 2 * 4096, b4, (unsigned char*)nullptr,
                                          graph_ids, gacc, 1, N);

    pool2_kernel<<<16, 256, 0, stream>>>(gacc, gcnt, Wout, bout, out);
}